// Round 11
// baseline (294.483 us; speedup 1.0000x reference)
//
#include <hip/hip_runtime.h>
#include <hip/hip_bf16.h>

#define N_TOK 8192
#define DIM   2048
#define NEXP  8
#define BM    288          // sum ceil(c_e/288) == 32 for c_e in [865,1152] -> 256 tiles
#define BN    256
#define BK    32
#define NT    (DIM / BK)   // 64 K-steps
#define NBLK  256          // persistent: exactly 1 block per CU

#define A_BYTES  (BM * BK * 2)            // 18432
#define B_BYTES  (BN * BK * 2)            // 16384
#define RING     (A_BYTES + B_BYTES)      // 34816
#define DYN_LDS  (4 * RING)               // 139264 (ring-4)

typedef __attribute__((ext_vector_type(8))) short  short8;
typedef __attribute__((ext_vector_type(4))) float  f32x4;
typedef __attribute__((ext_vector_type(4))) unsigned int u32x4;

static __device__ __forceinline__ unsigned int pack_bf2(float a, float b) {
  union { __hip_bfloat16 h; unsigned short u; } ca, cb;
  ca.h = __float2bfloat16(a);
  cb.h = __float2bfloat16(b);
  return ((unsigned int)cb.u << 16) | (unsigned int)ca.u;
}

static __device__ __forceinline__ void gload16(const unsigned short* g, void* l) {
  __builtin_amdgcn_global_load_lds(
      (const __attribute__((address_space(1))) unsigned int*)(const void*)g,
      (__attribute__((address_space(3))) unsigned int*)l, 16, 0, 0);
}

static __device__ __forceinline__ double dot8d(const float4& x0, const float4& x1,
                                               const float4& w0, const float4& w1) {
  double a = 0.0;
  a = fma((double)x0.x, (double)w0.x, a);
  a = fma((double)x0.y, (double)w0.y, a);
  a = fma((double)x0.z, (double)w0.z, a);
  a = fma((double)x0.w, (double)w0.w, a);
  a = fma((double)x1.x, (double)w1.x, a);
  a = fma((double)x1.y, (double)w1.y, a);
  a = fma((double)x1.z, (double)w1.z, a);
  a = fma((double)x1.w, (double)w1.w, a);
  return a;
}

// ---------------- router (unchanged, round 8) ----------------
__global__ __launch_bounds__(256, 3) void router_kernel(
    const float* __restrict__ x, const float* __restrict__ rw,
    const float* __restrict__ rb, int* __restrict__ eid,
    float* __restrict__ gate, unsigned short* __restrict__ xb)
{
  const int t    = threadIdx.x;
  const int tok0 = blockIdx.x * 4;

  float4 w0[NEXP], w1[NEXP];
#pragma unroll
  for (int e = 0; e < NEXP; e++) {
    const float4* wr = reinterpret_cast<const float4*>(rw + (size_t)e * DIM);
    w0[e] = wr[2 * t];
    w1[e] = wr[2 * t + 1];
  }
  float4 xv0[4], xv1[4];
#pragma unroll
  for (int k = 0; k < 4; k++) {
    const float4* xr = reinterpret_cast<const float4*>(x + (size_t)(tok0 + k) * DIM);
    xv0[k] = xr[2 * t];
    xv1[k] = xr[2 * t + 1];
  }
#pragma unroll
  for (int k = 0; k < 4; k++) {
    u32x4 pk;
    pk[0] = pack_bf2(xv0[k].x, xv0[k].y); pk[1] = pack_bf2(xv0[k].z, xv0[k].w);
    pk[2] = pack_bf2(xv1[k].x, xv1[k].y); pk[3] = pack_bf2(xv1[k].z, xv1[k].w);
    *reinterpret_cast<u32x4*>(xb + (size_t)(tok0 + k) * DIM + t * 8) = pk;
  }

  __shared__ double red[4][4][NEXP];
  const int lane = t & 63, wv = t >> 6;
#pragma unroll
  for (int k = 0; k < 4; k++) {
    double s[NEXP];
#pragma unroll
    for (int e = 0; e < NEXP; e++) s[e] = dot8d(xv0[k], xv1[k], w0[e], w1[e]);
#pragma unroll
    for (int e = 0; e < NEXP; e++) {
      double v = s[e];
#pragma unroll
      for (int off = 32; off > 0; off >>= 1) v += __shfl_xor(v, off, 64);
      if (lane == 0) red[wv][k][e] = v;
    }
  }
  __syncthreads();
  if (t < 4) {
    double lg[NEXP];
    double lmax = -1e300; int best = 0;
#pragma unroll
    for (int e = 0; e < NEXP; e++) {
      lg[e] = red[0][t][e] + red[1][t][e] + red[2][t][e] + red[3][t][e] + (double)rb[e];
      if (lg[e] > lmax) { lmax = lg[e]; best = e; }   // strict > == first-occurrence argmax
    }
    float den = 0.f;
#pragma unroll
    for (int e = 0; e < NEXP; e++) den += expf((float)(lg[e] - lmax));
    eid[tok0 + t]  = best;
    gate[tok0 + t] = 1.0f / den;
  }
}

// ---------------- histo + permute (unchanged, round 8) ----------------
__global__ __launch_bounds__(1024) void histo_perm(
    const int* __restrict__ eid, int* __restrict__ counts, int* __restrict__ perm)
{
  __shared__ int hist[NEXP], baseS[NEXP], fillS[NEXP];
  const int t = threadIdx.x;
  if (t < NEXP) { hist[t] = 0; fillS[t] = 0; }
  __syncthreads();
  int my[8];
#pragma unroll
  for (int i = 0; i < 8; i++) {
    my[i] = eid[t + i * 1024];
    atomicAdd(&hist[my[i]], 1);
  }
  __syncthreads();
  if (t == 0) {
    int b = 0;
#pragma unroll
    for (int e = 0; e < NEXP; e++) { counts[e] = hist[e]; baseS[e] = b; b += hist[e]; }
  }
  __syncthreads();
#pragma unroll
  for (int i = 0; i < 8; i++) {
    int pos = baseS[my[i]] + atomicAdd(&fillS[my[i]], 1);
    perm[pos] = t + i * 1024;
  }
}

// ------- grouped GEMM with FUSED W fp32->bf16 conversion (convw kernel eliminated) ----
// A: bf16 from xb via global_load_lds (3-slot-ahead).  B: fp32 W greads (2 ahead) ->
// cvt+ds_write (1 ahead) hidden under MFMA (T14 issue-early/write-late).
// Publish correctness WITHOUT counted vmcnt: cvt's auto-wait on B(t+1) drains A(t+1)
// (always older in the per-wave VMEM queue, by issue-order invariant); lgkmcnt(0)
// drains the ds_writes; the s_barrier then publishes slot t+1 group-wide.
#define LGKM0() asm volatile("s_waitcnt lgkmcnt(0)" ::: "memory")
#define BARM()  asm volatile("s_barrier" ::: "memory")

#define AGLOAD(GS)                                                          \
  do {                                                                      \
    gload16(aSrc[0], (GS) + aDst[0]);                                       \
    gload16(aSrc[1], (GS) + aDst[1]);                                       \
    if (nA5) gload16(aSrc[2], (GS) + aDst[2]);                              \
    aSrc[0] += BK; aSrc[1] += BK; aSrc[2] += BK;                            \
  } while (0)

#define BGREAD(BX, KT)                                                     \
  do {                                                                      \
    _Pragma("unroll")                                                       \
    for (int i = 0; i < 2; i++) {                                           \
      const float* p = wB32 + (size_t)(byBN + bR0[i] + (lane >> 2)) * DIM   \
                       + (KT) * BK + (lane & 3) * 8;                        \
      BX[2 * i]     = *reinterpret_cast<const float4*>(p);                  \
      BX[2 * i + 1] = *reinterpret_cast<const float4*>(p + 4);              \
    }                                                                       \
  } while (0)

#define CVTWRITE(BX, SLOT)                                                  \
  do {                                                                      \
    char* wb_ = smem + (SLOT) * RING;                                       \
    _Pragma("unroll")                                                       \
    for (int i = 0; i < 2; i++) {                                           \
      u32x4 pk;                                                             \
      pk[0] = pack_bf2(BX[2*i].x,   BX[2*i].y);                             \
      pk[1] = pack_bf2(BX[2*i].z,   BX[2*i].w);                             \
      pk[2] = pack_bf2(BX[2*i+1].x, BX[2*i+1].y);                           \
      pk[3] = pack_bf2(BX[2*i+1].z, BX[2*i+1].w);                           \
      *reinterpret_cast<u32x4*>(wb_ + bWr[i]) = pk;                         \
    }                                                                       \
  } while (0)

#define STEP(T, BL, BW)                                                     \
  do {                                                                      \
    if ((T) + 2 < NT) BGREAD(BL, (T) + 2);                                  \
    if ((T) + 3 < NT) AGLOAD(smem + (((T) + 3) & 3) * RING);                \
    if ((T) + 1 < NT) CVTWRITE(BW, ((T) + 1) & 3);                          \
    const char* cur = smem + ((T) & 3) * RING;                              \
    short8 af[9], bf[4];                                                    \
    _Pragma("unroll")                                                       \
    for (int n = 0; n < 4; n++) bf[n] = *(const short8*)(cur + bOff + n * 1024); \
    _Pragma("unroll")                                                       \
    for (int m = 0; m < 9; m++) af[m] = *(const short8*)(cur + aOff + m * 1024); \
    __builtin_amdgcn_s_setprio(1);                                          \
    _Pragma("unroll")                                                       \
    for (int m = 0; m < 9; m++)                                             \
      _Pragma("unroll")                                                     \
      for (int n = 0; n < 4; n++)                                           \
        acc[m][n] = __builtin_amdgcn_mfma_f32_16x16x32_bf16(af[m], bf[n],   \
                                                            acc[m][n], 0, 0, 0); \
    __builtin_amdgcn_s_setprio(0);                                          \
    if ((T) + 1 < NT) { LGKM0(); BARM(); }                                  \
  } while (0)

__global__ __launch_bounds__(512, 1) void moe_gemm(
    const unsigned short* __restrict__ xb, const float* __restrict__ ew,
    const float* __restrict__ eb, const float* __restrict__ gate,
    const int* __restrict__ perm, const int* __restrict__ counts,
    float* __restrict__ out)
{
  extern __shared__ char smem[];     // 4 ring slots of {A 18432 B | B 16384 B}
  __shared__ int   aRowS[BM];
  __shared__ float gateS[BM];

  const int tid  = threadIdx.x;
  const int lane = tid & 63, wid = tid >> 6;

  int ttot = 0;
#pragma unroll
  for (int j = 0; j < NEXP; j++) ttot += (counts[j] + BM - 1) / BM;
  ttot *= 8;

  // ---- A staging geometry (16-row chunks of 64B rows; 1KB per wave gload_lds) ----
  const int nA5 = (wid < 2);           // waves 0-1 carry a 3rd A chunk
  int aR0[3];
  aR0[0] = (wid * 2) * 16;
  aR0[1] = (wid * 2 + 1) * 16;
  aR0[2] = nA5 ? ((16 + wid) * 16) : aR0[0];
  int aDst[3];
#pragma unroll
  for (int i = 0; i < 3; i++) aDst[i] = aR0[i] * 64;
  const int lrow = lane >> 2;                          // row within 16-row chunk
  const int cblk = (lane & 3) ^ ((lane >> 3) & 3);     // pre-swizzled src block (involution)

  // ---- B staging geometry (reg-staged fp32 -> bf16; same swizzle applied on WRITE) ----
  int bR0[2];
  bR0[0] = (wid * 2) * 16;
  bR0[1] = (wid * 2 + 1) * 16;
  int bWr[2];
#pragma unroll
  for (int i = 0; i < 2; i++)
    bWr[i] = A_BYTES + (bR0[i] + (lane >> 2)) * 64 + (((lane & 3) ^ ((lane >> 3) & 3)) * 16);

  // ---- MFMA fragment addressing (2M x 4N waves; per-wave 144x64 output) ----
  const int l15 = lane & 15;
  const int wr = wid >> 2, wc = wid & 3;
  const int sw   = (((lane >> 4) ^ ((l15 >> 1) & 3)) * 16);   // read-side swizzle
  const int aOff = (wr * 144 + l15) * 64 + sw;
  const int bOff = A_BYTES + (wc * 64 + l15) * 64 + sw;
  const int rsub = (lane >> 4) * 4;

  for (int tt = blockIdx.x; tt < ttot; tt += NBLK) {
    const int bx = tt >> 3, by = tt & 7;
    const int byBN = by * BN;

    int e = 0, rowbase = 0, nrows = 0, found = 0;
    {
      int tsum = 0, bsum = 0;
#pragma unroll
      for (int j = 0; j < NEXP; j++) {
        int cj = counts[j];
        int te = (cj + BM - 1) / BM;
        if (!found && bx < tsum + te) {
          int loc = bx - tsum;
          e = j;
          rowbase = bsum + loc * BM;
          int rem = cj - loc * BM;
          nrows = rem < BM ? rem : BM;
          found = 1;
        }
        tsum += te; bsum += cj;
      }
    }

    __syncthreads();   // prior tile fully done with aRowS/gateS and LDS slots
    if (tid < BM) {
      int idx = tid < nrows ? tid : (nrows - 1);
      int tok = perm[rowbase + idx];
      aRowS[tid] = tok;
      gateS[tid] = gate[tok];
    }
    __syncthreads();

    const float* wB32 = ew + (size_t)e * DIM * DIM;
    const unsigned short* aSrc[3];
#pragma unroll
    for (int i = 0; i < 3; i++)
      aSrc[i] = xb + (size_t)aRowS[aR0[i] + lrow] * DIM + cblk * 8;

    float4 bX[4], bY[4];

    // ---- prologue: interleave A(k) before B(k) so cvt's auto-wait drains A too ----
    AGLOAD(smem);                 // A(0) -> slot 0
    BGREAD(bX, 0);                // B(0) -> regs
    AGLOAD(smem + RING);          // A(1) -> slot 1
    BGREAD(bY, 1);                // B(1) -> regs
    AGLOAD(smem + 2 * RING);      // A(2) -> slot 2
    CVTWRITE(bX, 0);              // auto-vmcnt drains A(0)+B(0); write B(0) -> slot 0
    LGKM0();
    BARM();                       // publish slot 0

    f32x4 acc[9][4] = {};

#pragma unroll 1
    for (int t = 0; t < NT; t += 2) {
      STEP(t,     bX, bY);        // gread B(t+2)->bX, write B(t+1)=bY, MFMA(t)
      STEP(t + 1, bY, bX);        // gread B(t+3)->bY, write B(t+2)=bX, MFMA(t+1)
    }

    // ---- epilogue: +bias, *gate, scatter by token ----
    const int cb = byBN + wc * 64;
    const float* ebE = eb + (size_t)e * DIM;
    float bias[4];
#pragma unroll
    for (int n = 0; n < 4; n++) bias[n] = ebE[cb + n * 16 + l15];
#pragma unroll
    for (int m = 0; m < 9; m++) {
      int r0 = wr * 144 + m * 16 + rsub;
#pragma unroll
      for (int rg = 0; rg < 4; rg++) {
        int r = r0 + rg;
        if (r < nrows) {
          float g = gateS[r];
          float* orow = out + (size_t)aRowS[r] * DIM + cb;
#pragma unroll
          for (int n = 0; n < 4; n++)
            orow[n * 16 + l15] = (acc[m][n][rg] + bias[n]) * g;
        }
      }
    }
  }
}

extern "C" void kernel_launch(void* const* d_in, const int* in_sizes, int n_in,
                              void* d_out, int out_size, void* d_ws, size_t ws_size,
                              hipStream_t stream)
{
  const float* x  = (const float*)d_in[0];
  const float* ew = (const float*)d_in[1];
  const float* eb = (const float*)d_in[2];
  const float* rw = (const float*)d_in[3];
  const float* rb = (const float*)d_in[4];
  float* out = (float*)d_out;

  char* ws = (char*)d_ws;
  int*   eid    = (int*)(ws);                  // 8192 ints
  float* gate   = (float*)(ws + 32 * 1024);    // 8192 floats
  int*   counts = (int*)(ws + 64 * 1024);      // [0..7]
  int*   perm   = (int*)(ws + 128 * 1024);     // 8192 ints
  unsigned short* xbuf = (unsigned short*)(ws + 192 * 1024);   // 32 MB

  hipFuncSetAttribute(reinterpret_cast<const void*>(moe_gemm),
                      hipFuncAttributeMaxDynamicSharedMemorySize, DYN_LDS);

  hipMemsetAsync(out + (size_t)N_TOK * DIM, 0, sizeof(float), stream);      // loss = 0
  router_kernel<<<N_TOK / 4, 256, 0, stream>>>(x, rw, rb, eid, gate, xbuf);
  histo_perm<<<1, 1024, 0, stream>>>(eid, counts, perm);
  moe_gemm<<<NBLK, 512, DYN_LDS, stream>>>(xbuf, ew, eb, gate, perm, counts, out);
}

// Round 12
// 173.056 us; speedup vs baseline: 1.7017x; 1.7017x over previous
//
#include <hip/hip_runtime.h>
#include <hip/hip_bf16.h>

#define N_TOK 8192
#define DIM   2048
#define NEXP  8
#define BM    288          // sum ceil(c_e/288) == 32 for c_e in [865,1152] -> 256 tiles
#define BN    256
#define BK    32
#define NT    (DIM / BK)   // 64 K-steps
#define NBLK  256          // persistent: exactly 1 block per CU

#define A_BYTES  (BM * BK * 2)            // 18432
#define B_BYTES  (BN * BK * 2)            // 16384
#define RING     (A_BYTES + B_BYTES)      // 34816
#define DYN_LDS  (4 * RING)               // 139264 (ring-4)

typedef __attribute__((ext_vector_type(8))) short  short8;
typedef __attribute__((ext_vector_type(4))) float  f32x4;
typedef __attribute__((ext_vector_type(4))) unsigned int u32x4;

static __device__ __forceinline__ unsigned int pack_bf2(float a, float b) {
  union { __hip_bfloat16 h; unsigned short u; } ca, cb;
  ca.h = __float2bfloat16(a);
  cb.h = __float2bfloat16(b);
  return ((unsigned int)cb.u << 16) | (unsigned int)ca.u;
}

static __device__ __forceinline__ void gload16(const unsigned short* g, void* l) {
  __builtin_amdgcn_global_load_lds(
      (const __attribute__((address_space(1))) unsigned int*)(const void*)g,
      (__attribute__((address_space(3))) unsigned int*)l, 16, 0, 0);
}

static __device__ __forceinline__ double dot8d(const float4& x0, const float4& x1,
                                               const float4& w0, const float4& w1) {
  double a = 0.0;
  a = fma((double)x0.x, (double)w0.x, a);
  a = fma((double)x0.y, (double)w0.y, a);
  a = fma((double)x0.z, (double)w0.z, a);
  a = fma((double)x0.w, (double)w0.w, a);
  a = fma((double)x1.x, (double)w1.x, a);
  a = fma((double)x1.y, (double)w1.y, a);
  a = fma((double)x1.z, (double)w1.z, a);
  a = fma((double)x1.w, (double)w1.w, a);
  return a;
}

// ---------------- W -> bf16 convert (unchanged, round 8) ----------------
__global__ __launch_bounds__(256) void convw_kernel(
    const float* __restrict__ w, unsigned short* __restrict__ wbuf)
{
  const size_t c0 = (size_t)blockIdx.x * 1024 + threadIdx.x;
  float4 f[8];
#pragma unroll
  for (int i = 0; i < 4; i++) {
    const float4* s = reinterpret_cast<const float4*>(w + (c0 + i * 256) * 8);
    f[2 * i]     = s[0];
    f[2 * i + 1] = s[1];
  }
#pragma unroll
  for (int i = 0; i < 4; i++) {
    u32x4 pk;
    pk[0] = pack_bf2(f[2*i].x,   f[2*i].y);   pk[1] = pack_bf2(f[2*i].z,   f[2*i].w);
    pk[2] = pack_bf2(f[2*i+1].x, f[2*i+1].y); pk[3] = pack_bf2(f[2*i+1].z, f[2*i+1].w);
    *reinterpret_cast<u32x4*>(wbuf + (c0 + i * 256) * 8) = pk;
  }
}

// ---------------- router (unchanged, round 8) ----------------
__global__ __launch_bounds__(256, 3) void router_kernel(
    const float* __restrict__ x, const float* __restrict__ rw,
    const float* __restrict__ rb, int* __restrict__ eid,
    float* __restrict__ gate, unsigned short* __restrict__ xb)
{
  const int t    = threadIdx.x;
  const int tok0 = blockIdx.x * 4;

  float4 w0[NEXP], w1[NEXP];
#pragma unroll
  for (int e = 0; e < NEXP; e++) {
    const float4* wr = reinterpret_cast<const float4*>(rw + (size_t)e * DIM);
    w0[e] = wr[2 * t];
    w1[e] = wr[2 * t + 1];
  }
  float4 xv0[4], xv1[4];
#pragma unroll
  for (int k = 0; k < 4; k++) {
    const float4* xr = reinterpret_cast<const float4*>(x + (size_t)(tok0 + k) * DIM);
    xv0[k] = xr[2 * t];
    xv1[k] = xr[2 * t + 1];
  }
#pragma unroll
  for (int k = 0; k < 4; k++) {
    u32x4 pk;
    pk[0] = pack_bf2(xv0[k].x, xv0[k].y); pk[1] = pack_bf2(xv0[k].z, xv0[k].w);
    pk[2] = pack_bf2(xv1[k].x, xv1[k].y); pk[3] = pack_bf2(xv1[k].z, xv1[k].w);
    *reinterpret_cast<u32x4*>(xb + (size_t)(tok0 + k) * DIM + t * 8) = pk;
  }

  __shared__ double red[4][4][NEXP];
  const int lane = t & 63, wv = t >> 6;
#pragma unroll
  for (int k = 0; k < 4; k++) {
    double s[NEXP];
#pragma unroll
    for (int e = 0; e < NEXP; e++) s[e] = dot8d(xv0[k], xv1[k], w0[e], w1[e]);
#pragma unroll
    for (int e = 0; e < NEXP; e++) {
      double v = s[e];
#pragma unroll
      for (int off = 32; off > 0; off >>= 1) v += __shfl_xor(v, off, 64);
      if (lane == 0) red[wv][k][e] = v;
    }
  }
  __syncthreads();
  if (t < 4) {
    double lg[NEXP];
    double lmax = -1e300; int best = 0;
#pragma unroll
    for (int e = 0; e < NEXP; e++) {
      lg[e] = red[0][t][e] + red[1][t][e] + red[2][t][e] + red[3][t][e] + (double)rb[e];
      if (lg[e] > lmax) { lmax = lg[e]; best = e; }   // strict > == first-occurrence argmax
    }
    float den = 0.f;
#pragma unroll
    for (int e = 0; e < NEXP; e++) den += expf((float)(lg[e] - lmax));
    eid[tok0 + t]  = best;
    gate[tok0 + t] = 1.0f / den;
  }
}

// ---------------- histo + permute (unchanged, round 8) ----------------
__global__ __launch_bounds__(1024) void histo_perm(
    const int* __restrict__ eid, int* __restrict__ counts, int* __restrict__ perm)
{
  __shared__ int hist[NEXP], baseS[NEXP], fillS[NEXP];
  const int t = threadIdx.x;
  if (t < NEXP) { hist[t] = 0; fillS[t] = 0; }
  __syncthreads();
  int my[8];
#pragma unroll
  for (int i = 0; i < 8; i++) {
    my[i] = eid[t + i * 1024];
    atomicAdd(&hist[my[i]], 1);
  }
  __syncthreads();
  if (t == 0) {
    int b = 0;
#pragma unroll
    for (int e = 0; e < NEXP; e++) { counts[e] = hist[e]; baseS[e] = b; b += hist[e]; }
  }
  __syncthreads();
#pragma unroll
  for (int i = 0; i < 8; i++) {
    int pos = baseS[my[i]] + atomicAdd(&fillS[my[i]], 1);
    perm[pos] = t + i * 1024;
  }
}

// ------- grouped GEMM: round-8 loop + m204 bijective XCD tile grouping ---------------
// Locality fix: persistent block b (XCD = b%8 heuristic) owns a CONTIGUOUS bx-major
// tile range -> each XCD's 32 blocks span ~4 A row-panels x 8 B col-panels; active
// K-window working set (~3 MB) fits the XCD's 4 MB L2, so A panels are fetched from
// L3 once per XCD-group instead of 8x. Mapping is bijective for any ttot (m204).
__global__ __launch_bounds__(512, 2) void moe_gemm(
    const unsigned short* __restrict__ xb, const unsigned short* __restrict__ wb,
    const float* __restrict__ eb, const float* __restrict__ gate,
    const int* __restrict__ perm, const int* __restrict__ counts,
    float* __restrict__ out)
{
  extern __shared__ char smem[];     // 4 ring slots of {A 18432 B | B 16384 B}
  __shared__ int   aRowS[BM];
  __shared__ float gateS[BM];

  const int tid  = threadIdx.x;
  const int lane = tid & 63, wid = tid >> 6;

  int ttot = 0;
#pragma unroll
  for (int j = 0; j < NEXP; j++) ttot += (counts[j] + BM - 1) / BM;
  ttot *= 8;
  const int tq = ttot >> 3, tr = ttot & 7;

  // ---- staging geometry (16-row chunks of 64B rows; 1KB per wave-load) ----
  const int nA5 = (wid < 2);           // waves 0-1 carry a 3rd A chunk
  int aR0[3], bR0[2];
  aR0[0] = (wid * 2) * 16;
  aR0[1] = (wid * 2 + 1) * 16;
  aR0[2] = nA5 ? ((16 + wid) * 16) : aR0[0];
  bR0[0] = (wid * 2) * 16;
  bR0[1] = (wid * 2 + 1) * 16;
  int aDst[3], bDst[2];
#pragma unroll
  for (int i = 0; i < 3; i++) aDst[i] = aR0[i] * 64;
#pragma unroll
  for (int i = 0; i < 2; i++) bDst[i] = A_BYTES + bR0[i] * 64;
  const int lrow = lane >> 2;                          // row within 16-row chunk
  const int cblk = (lane & 3) ^ ((lane >> 3) & 3);     // pre-swizzled src block (involution)

  // ---- MFMA fragment addressing (2M x 4N waves; per-wave 144x64 output) ----
  const int l15 = lane & 15;
  const int wr = wid >> 2, wc = wid & 3;
  const int sw   = (((lane >> 4) ^ ((l15 >> 1) & 3)) * 16);   // read-side swizzle
  const int aOff = (wr * 144 + l15) * 64 + sw;
  const int bOff = A_BYTES + (wc * 64 + l15) * 64 + sw;
  const int rsub = (lane >> 4) * 4;

  for (int ti = blockIdx.x; ti < ttot; ti += NBLK) {
    // ---- m204 bijective XCD remap: XCD k = ti&7 owns contiguous bx-major range ----
    const int k  = ti & 7, j = ti >> 3;
    const int tt = k * tq + (k < tr ? k : tr) + j;     // logical tile (bx-major)
    const int bx = tt >> 3, by = tt & 7;

    int e = 0, rowbase = 0, nrows = 0, found = 0;
    {
      int tsum = 0, bsum = 0;
#pragma unroll
      for (int jj = 0; jj < NEXP; jj++) {
        int cj = counts[jj];
        int te = (cj + BM - 1) / BM;
        if (!found && bx < tsum + te) {
          int loc = bx - tsum;
          e = jj;
          rowbase = bsum + loc * BM;
          int rem = cj - loc * BM;
          nrows = rem < BM ? rem : BM;
          found = 1;
        }
        tsum += te; bsum += cj;
      }
    }

    __syncthreads();   // prior tile fully done with aRowS/gateS and LDS slots
    if (tid < BM) {
      int idx = tid < nrows ? tid : (nrows - 1);
      int tok = perm[rowbase + idx];
      aRowS[tid] = tok;
      gateS[tid] = gate[tok];
    }
    __syncthreads();

    const unsigned short* wB = wb + (size_t)e * DIM * DIM;
    const unsigned short* aSrc[3];
    const unsigned short* bSrc[2];
#pragma unroll
    for (int i = 0; i < 3; i++)
      aSrc[i] = xb + (size_t)aRowS[aR0[i] + lrow] * DIM + cblk * 8;
#pragma unroll
    for (int i = 0; i < 2; i++)
      bSrc[i] = wB + (size_t)(by * BN + bR0[i] + lrow) * DIM + cblk * 8;

    // ---- prologue: stage K-steps 0..2 into ring slots 0..2 ----
#pragma unroll
    for (int p = 0; p < 3; p++) {
      char* base = smem + p * RING;
      gload16(aSrc[0], base + aDst[0]);
      gload16(aSrc[1], base + aDst[1]);
      if (nA5) gload16(aSrc[2], base + aDst[2]);
      gload16(bSrc[0], base + bDst[0]);
      gload16(bSrc[1], base + bDst[1]);
      aSrc[0] += BK; aSrc[1] += BK; aSrc[2] += BK;
      bSrc[0] += BK; bSrc[1] += BK;
    }

    f32x4 acc[9][4] = {};

#pragma unroll 1
    for (int t = 0; t < NT; ++t) {
      // counted wait on OWN loads of step t, BEFORE the publishing barrier
      if (t < NT - 2) {
        if (nA5) asm volatile("s_waitcnt vmcnt(10)" ::: "memory");
        else     asm volatile("s_waitcnt vmcnt(8)"  ::: "memory");
      } else if (t == NT - 2) {
        if (nA5) asm volatile("s_waitcnt vmcnt(5)" ::: "memory");
        else     asm volatile("s_waitcnt vmcnt(4)" ::: "memory");
      } else {
        asm volatile("s_waitcnt vmcnt(0)" ::: "memory");
      }
      __builtin_amdgcn_s_barrier();   // publishes step-t loads; slot (t-1)&3 free

      if (t + 3 < NT) {               // prefetch step t+3 into slot (t+3)&3
        char* base = smem + ((t + 3) & 3) * RING;
        gload16(aSrc[0], base + aDst[0]);
        gload16(aSrc[1], base + aDst[1]);
        if (nA5) gload16(aSrc[2], base + aDst[2]);
        gload16(bSrc[0], base + bDst[0]);
        gload16(bSrc[1], base + bDst[1]);
        aSrc[0] += BK; aSrc[1] += BK; aSrc[2] += BK;
        bSrc[0] += BK; bSrc[1] += BK;
      }

      const char* cur = smem + (t & 3) * RING;
      short8 af[9], bf[4];
#pragma unroll
      for (int n = 0; n < 4; n++) bf[n] = *(const short8*)(cur + bOff + n * 1024);
#pragma unroll
      for (int m = 0; m < 9; m++) af[m] = *(const short8*)(cur + aOff + m * 1024);
      __builtin_amdgcn_s_setprio(1);
#pragma unroll
      for (int m = 0; m < 9; m++)
#pragma unroll
        for (int n = 0; n < 4; n++)
          acc[m][n] = __builtin_amdgcn_mfma_f32_16x16x32_bf16(af[m], bf[n], acc[m][n], 0, 0, 0);
      __builtin_amdgcn_s_setprio(0);
    }

    // ---- epilogue: +bias, *gate, scatter by token ----
    const int cb = by * BN + wc * 64;
    const float* ebE = eb + (size_t)e * DIM;
    float bias[4];
#pragma unroll
    for (int n = 0; n < 4; n++) bias[n] = ebE[cb + n * 16 + l15];
#pragma unroll
    for (int m = 0; m < 9; m++) {
      int r0 = wr * 144 + m * 16 + rsub;
#pragma unroll
      for (int rg = 0; rg < 4; rg++) {
        int r = r0 + rg;
        if (r < nrows) {
          float g = gateS[r];
          float* orow = out + (size_t)aRowS[r] * DIM + cb;
#pragma unroll
          for (int n = 0; n < 4; n++)
            orow[n * 16 + l15] = (acc[m][n][rg] + bias[n]) * g;
        }
      }
    }
    asm volatile("s_waitcnt vmcnt(0)" ::: "memory");   // drain stores before next tile
  }
}

extern "C" void kernel_launch(void* const* d_in, const int* in_sizes, int n_in,
                              void* d_out, int out_size, void* d_ws, size_t ws_size,
                              hipStream_t stream)
{
  const float* x  = (const float*)d_in[0];
  const float* ew = (const float*)d_in[1];
  const float* eb = (const float*)d_in[2];
  const float* rw = (const float*)d_in[3];
  const float* rb = (const float*)d_in[4];
  float* out = (float*)d_out;

  char* ws = (char*)d_ws;
  int*   eid    = (int*)(ws);                  // 8192 ints
  float* gate   = (float*)(ws + 32 * 1024);    // 8192 floats
  int*   counts = (int*)(ws + 64 * 1024);      // [0..7]
  int*   perm   = (int*)(ws + 128 * 1024);     // 8192 ints
  unsigned short* xbuf = (unsigned short*)(ws + 192 * 1024);                               // 32 MB
  unsigned short* wbuf = (unsigned short*)(ws + 192 * 1024 + ((size_t)N_TOK * DIM * 2));   // 64 MB

  hipFuncSetAttribute(reinterpret_cast<const void*>(moe_gemm),
                      hipFuncAttributeMaxDynamicSharedMemorySize, DYN_LDS);

  hipMemsetAsync(out + (size_t)N_TOK * DIM, 0, sizeof(float), stream);      // loss = 0
  convw_kernel<<<4096, 256, 0, stream>>>(ew, wbuf);
  router_kernel<<<N_TOK / 4, 256, 0, stream>>>(x, rw, rb, eid, gate, xbuf);
  histo_perm<<<1, 1024, 0, stream>>>(eid, counts, perm);
  moe_gemm<<<NBLK, 512, DYN_LDS, stream>>>(xbuf, wbuf, eb, gate, perm, counts, out);
}

// Round 13
// 155.256 us; speedup vs baseline: 1.8968x; 1.1147x over previous
//
#include <hip/hip_runtime.h>
#include <hip/hip_bf16.h>

#define N_TOK 8192
#define DIM   2048
#define NEXP  8
#define BM    288          // sum ceil(c_e/288) == 32 for c_e in [865,1152] -> 256 tiles
#define BN    256
#define BK    32
#define NT    (DIM / BK)   // 64 K-steps
#define NBLK  256          // persistent: exactly 1 block per CU

#define A_BYTES  (BM * BK * 2)            // 18432 (A: bf16)
#define B_BYTES  (BN * BK * 4)            // 32768 (B: fp32, converted on LDS->reg read)
#define RING     (A_BYTES + B_BYTES)      // 51200
#define DYN_LDS  (3 * RING)               // 153600 (ring-3)

typedef __attribute__((ext_vector_type(8))) short  short8;
typedef __attribute__((ext_vector_type(4))) float  f32x4;
typedef __attribute__((ext_vector_type(4))) unsigned int u32x4;

static __device__ __forceinline__ unsigned int pack_bf2(float a, float b) {
  union { __hip_bfloat16 h; unsigned short u; } ca, cb;
  ca.h = __float2bfloat16(a);
  cb.h = __float2bfloat16(b);
  return ((unsigned int)cb.u << 16) | (unsigned int)ca.u;
}

static __device__ __forceinline__ void gload16(const void* g, void* l) {
  __builtin_amdgcn_global_load_lds(
      (const __attribute__((address_space(1))) unsigned int*)g,
      (__attribute__((address_space(3))) unsigned int*)l, 16, 0, 0);
}

static __device__ __forceinline__ double dot8d(const float4& x0, const float4& x1,
                                               const float4& w0, const float4& w1) {
  double a = 0.0;
  a = fma((double)x0.x, (double)w0.x, a);
  a = fma((double)x0.y, (double)w0.y, a);
  a = fma((double)x0.z, (double)w0.z, a);
  a = fma((double)x0.w, (double)w0.w, a);
  a = fma((double)x1.x, (double)w1.x, a);
  a = fma((double)x1.y, (double)w1.y, a);
  a = fma((double)x1.z, (double)w1.z, a);
  a = fma((double)x1.w, (double)w1.w, a);
  return a;
}

// ---------------- router (unchanged, round 8) ----------------
__global__ __launch_bounds__(256, 3) void router_kernel(
    const float* __restrict__ x, const float* __restrict__ rw,
    const float* __restrict__ rb, int* __restrict__ eid,
    float* __restrict__ gate, unsigned short* __restrict__ xb)
{
  const int t    = threadIdx.x;
  const int tok0 = blockIdx.x * 4;

  float4 w0[NEXP], w1[NEXP];
#pragma unroll
  for (int e = 0; e < NEXP; e++) {
    const float4* wr = reinterpret_cast<const float4*>(rw + (size_t)e * DIM);
    w0[e] = wr[2 * t];
    w1[e] = wr[2 * t + 1];
  }
  float4 xv0[4], xv1[4];
#pragma unroll
  for (int k = 0; k < 4; k++) {
    const float4* xr = reinterpret_cast<const float4*>(x + (size_t)(tok0 + k) * DIM);
    xv0[k] = xr[2 * t];
    xv1[k] = xr[2 * t + 1];
  }
#pragma unroll
  for (int k = 0; k < 4; k++) {
    u32x4 pk;
    pk[0] = pack_bf2(xv0[k].x, xv0[k].y); pk[1] = pack_bf2(xv0[k].z, xv0[k].w);
    pk[2] = pack_bf2(xv1[k].x, xv1[k].y); pk[3] = pack_bf2(xv1[k].z, xv1[k].w);
    *reinterpret_cast<u32x4*>(xb + (size_t)(tok0 + k) * DIM + t * 8) = pk;
  }

  __shared__ double red[4][4][NEXP];
  const int lane = t & 63, wv = t >> 6;
#pragma unroll
  for (int k = 0; k < 4; k++) {
    double s[NEXP];
#pragma unroll
    for (int e = 0; e < NEXP; e++) s[e] = dot8d(xv0[k], xv1[k], w0[e], w1[e]);
#pragma unroll
    for (int e = 0; e < NEXP; e++) {
      double v = s[e];
#pragma unroll
      for (int off = 32; off > 0; off >>= 1) v += __shfl_xor(v, off, 64);
      if (lane == 0) red[wv][k][e] = v;
    }
  }
  __syncthreads();
  if (t < 4) {
    double lg[NEXP];
    double lmax = -1e300; int best = 0;
#pragma unroll
    for (int e = 0; e < NEXP; e++) {
      lg[e] = red[0][t][e] + red[1][t][e] + red[2][t][e] + red[3][t][e] + (double)rb[e];
      if (lg[e] > lmax) { lmax = lg[e]; best = e; }   // strict > == first-occurrence argmax
    }
    float den = 0.f;
#pragma unroll
    for (int e = 0; e < NEXP; e++) den += expf((float)(lg[e] - lmax));
    eid[tok0 + t]  = best;
    gate[tok0 + t] = 1.0f / den;
  }
}

// ---------------- histo + permute (unchanged, round 8) ----------------
__global__ __launch_bounds__(1024) void histo_perm(
    const int* __restrict__ eid, int* __restrict__ counts, int* __restrict__ perm)
{
  __shared__ int hist[NEXP], baseS[NEXP], fillS[NEXP];
  const int t = threadIdx.x;
  if (t < NEXP) { hist[t] = 0; fillS[t] = 0; }
  __syncthreads();
  int my[8];
#pragma unroll
  for (int i = 0; i < 8; i++) {
    my[i] = eid[t + i * 1024];
    atomicAdd(&hist[my[i]], 1);
  }
  __syncthreads();
  if (t == 0) {
    int b = 0;
#pragma unroll
    for (int e = 0; e < NEXP; e++) { counts[e] = hist[e]; baseS[e] = b; b += hist[e]; }
  }
  __syncthreads();
#pragma unroll
  for (int i = 0; i < 8; i++) {
    int pos = baseS[my[i]] + atomicAdd(&fillS[my[i]], 1);
    perm[pos] = t + i * 1024;
  }
}

// ------- grouped GEMM: B staged fp32 direct from W (convw eliminated), ring-3 -------
// A: bf16 from xb via global_load_lds.  B: fp32 W via global_load_lds (pre-swizzled
// source, involution chunk^=row&7 on 128B rows), converted bf16 on the LDS->reg path
// (2x ds_read_b128 + 4 packs per frag; no long-lived staging regs -> no spill).
// Publish discipline (round 6): own counted vmcnt BEFORE the barrier; prefetch dist 2.
__global__ __launch_bounds__(512, 2) void moe_gemm(
    const unsigned short* __restrict__ xb, const float* __restrict__ ew,
    const float* __restrict__ eb, const float* __restrict__ gate,
    const int* __restrict__ perm, const int* __restrict__ counts,
    float* __restrict__ out)
{
  extern __shared__ char smem[];     // 3 ring slots of {A 18432 B bf16 | B 32768 B fp32}
  __shared__ int   aRowS[BM];
  __shared__ float gateS[BM];

  const int tid  = threadIdx.x;
  const int lane = tid & 63, wid = tid >> 6;

  int ttot = 0;
#pragma unroll
  for (int j = 0; j < NEXP; j++) ttot += (counts[j] + BM - 1) / BM;
  ttot *= 8;
  const int tq = ttot >> 3, tr = ttot & 7;

  // ---- A staging geometry (16-row chunks of 64B bf16 rows; 1KB per gload16) ----
  const int nA5 = (wid < 2);           // waves 0-1 carry a 3rd A chunk (18 chunks total)
  int aR0[3];
  aR0[0] = (wid * 2) * 16;
  aR0[1] = (wid * 2 + 1) * 16;
  aR0[2] = nA5 ? ((16 + wid) * 16) : aR0[0];
  int aDst[3];
#pragma unroll
  for (int i = 0; i < 3; i++) aDst[i] = aR0[i] * 64;
  const int lrowA = lane >> 2;                          // row within 16-row chunk
  const int cblkA = (lane & 3) ^ ((lane >> 3) & 3);     // pre-swizzled src (involution)

  // ---- B staging geometry (8-row chunks of 128B fp32 rows; 1KB per gload16) ----
  int bR0[4];
#pragma unroll
  for (int i = 0; i < 4; i++) bR0[i] = wid * 32 + i * 8;
  int bDst[4];
#pragma unroll
  for (int i = 0; i < 4; i++) bDst[i] = A_BYTES + bR0[i] * 128;
  const int lrowB = lane >> 3;                          // row within 8-row chunk
  const int cblkB = (lane & 7) ^ (lrowB & 7);           // pre-swizzled src (involution)

  // ---- MFMA fragment addressing (2M x 4N waves; per-wave 144x64 output) ----
  const int l15 = lane & 15;
  const int wr = wid >> 2, wc = wid & 3;
  const int swA  = (((lane >> 4) ^ ((l15 >> 1) & 3)) * 16);   // A read-side swizzle
  const int aOff = (wr * 144 + l15) * 64 + swA;
  const int csB  = (lane >> 4) * 2;                           // fp32 16B-chunk pair base
  int bOffN[4];                                               // B frag read offsets (c0)
#pragma unroll
  for (int n = 0; n < 4; n++) {
    int row = wc * 64 + n * 16 + l15;
    bOffN[n] = A_BYTES + row * 128 + ((csB ^ (row & 7)) << 4);   // c1 = c0 ^ 16
  }
  const int rsub = (lane >> 4) * 4;

  for (int ti = blockIdx.x; ti < ttot; ti += NBLK) {
    // ---- m204 bijective XCD remap: XCD k = ti&7 owns contiguous bx-major range ----
    const int k  = ti & 7, j = ti >> 3;
    const int tt = k * tq + (k < tr ? k : tr) + j;     // logical tile (bx-major)
    const int bx = tt >> 3, by = tt & 7;

    int e = 0, rowbase = 0, nrows = 0, found = 0;
    {
      int tsum = 0, bsum = 0;
#pragma unroll
      for (int jj = 0; jj < NEXP; jj++) {
        int cj = counts[jj];
        int te = (cj + BM - 1) / BM;
        if (!found && bx < tsum + te) {
          int loc = bx - tsum;
          e = jj;
          rowbase = bsum + loc * BM;
          int rem = cj - loc * BM;
          nrows = rem < BM ? rem : BM;
          found = 1;
        }
        tsum += te; bsum += cj;
      }
    }

    __syncthreads();   // prior tile fully done with aRowS/gateS and LDS slots
    if (tid < BM) {
      int idx = tid < nrows ? tid : (nrows - 1);
      int tok = perm[rowbase + idx];
      aRowS[tid] = tok;
      gateS[tid] = gate[tok];
    }
    __syncthreads();

    const float* wB32 = ew + (size_t)e * DIM * DIM;
    const unsigned short* aSrc[3];
    const float* bSrc[4];
#pragma unroll
    for (int i = 0; i < 3; i++)
      aSrc[i] = xb + (size_t)aRowS[aR0[i] + lrowA] * DIM + cblkA * 8;
#pragma unroll
    for (int i = 0; i < 4; i++)
      bSrc[i] = wB32 + (size_t)(by * BN + bR0[i] + lrowB) * DIM + cblkB * 4;

#define STAGE(SLOTP)                                                        \
    do {                                                                    \
      char* sb_ = (SLOTP);                                                  \
      gload16(aSrc[0], sb_ + aDst[0]);                                      \
      gload16(aSrc[1], sb_ + aDst[1]);                                      \
      if (nA5) gload16(aSrc[2], sb_ + aDst[2]);                             \
      gload16(bSrc[0], sb_ + bDst[0]);                                      \
      gload16(bSrc[1], sb_ + bDst[1]);                                      \
      gload16(bSrc[2], sb_ + bDst[2]);                                      \
      gload16(bSrc[3], sb_ + bDst[3]);                                      \
      aSrc[0] += BK; aSrc[1] += BK; aSrc[2] += BK;                          \
      bSrc[0] += BK; bSrc[1] += BK; bSrc[2] += BK; bSrc[3] += BK;           \
    } while (0)

    // ---- prologue: stage K-steps 0,1 into ring slots 0,1 ----
    STAGE(smem);
    STAGE(smem + RING);

    f32x4 acc[9][4] = {};

#pragma unroll 1
    for (int t = 0; t < NT; ++t) {
      // counted wait on OWN loads of slot t (one step's batch stays in flight)
      if (t < NT - 1) {
        if (nA5) asm volatile("s_waitcnt vmcnt(7)" ::: "memory");
        else     asm volatile("s_waitcnt vmcnt(6)" ::: "memory");
      } else {
        asm volatile("s_waitcnt vmcnt(0)" ::: "memory");
      }
      __builtin_amdgcn_s_barrier();   // publishes slot t; slot (t-1)%3 now free

      if (t + 2 < NT) {
        int slot = t + 2;
        slot -= (slot >= 3) ? 3 : 0;
        slot -= (slot >= 3) ? 3 : 0;   // (t+2) mod 3 without div (t+2 <= 65)
        STAGE(smem + (size_t)((t + 2) % 3) * RING);
        (void)slot;
      }

      const char* cur = smem + (size_t)(t % 3) * RING;

      // ---- B: fp32 ds_read + convert to bf16 frags ----
      f32x4 r0[4], r1[4];
#pragma unroll
      for (int n = 0; n < 4; n++) {
        r0[n] = *(const f32x4*)(cur + bOffN[n]);
        r1[n] = *(const f32x4*)(cur + (bOffN[n] ^ 16));
      }
      short8 bf[4];
#pragma unroll
      for (int n = 0; n < 4; n++) {
        u32x4 pk;
        pk[0] = pack_bf2(r0[n][0], r0[n][1]);
        pk[1] = pack_bf2(r0[n][2], r0[n][3]);
        pk[2] = pack_bf2(r1[n][0], r1[n][1]);
        pk[3] = pack_bf2(r1[n][2], r1[n][3]);
        union { u32x4 u; short8 s; } cv;
        cv.u = pk;
        bf[n] = cv.s;
      }
      // ---- A: bf16 ds_read frags ----
      short8 af[9];
#pragma unroll
      for (int m = 0; m < 9; m++) af[m] = *(const short8*)(cur + aOff + m * 1024);

      __builtin_amdgcn_s_setprio(1);
#pragma unroll
      for (int m = 0; m < 9; m++)
#pragma unroll
        for (int n = 0; n < 4; n++)
          acc[m][n] = __builtin_amdgcn_mfma_f32_16x16x32_bf16(af[m], bf[n], acc[m][n], 0, 0, 0);
      __builtin_amdgcn_s_setprio(0);
    }
#undef STAGE

    // ---- epilogue: +bias, *gate, scatter by token ----
    const int cb = by * BN + wc * 64;
    const float* ebE = eb + (size_t)e * DIM;
    float bias[4];
#pragma unroll
    for (int n = 0; n < 4; n++) bias[n] = ebE[cb + n * 16 + l15];
#pragma unroll
    for (int m = 0; m < 9; m++) {
      int r0w = wr * 144 + m * 16 + rsub;
#pragma unroll
      for (int rg = 0; rg < 4; rg++) {
        int r = r0w + rg;
        if (r < nrows) {
          float g = gateS[r];
          float* orow = out + (size_t)aRowS[r] * DIM + cb;
#pragma unroll
          for (int n = 0; n < 4; n++)
            orow[n * 16 + l15] = (acc[m][n][rg] + bias[n]) * g;
        }
      }
    }
    asm volatile("s_waitcnt vmcnt(0)" ::: "memory");   // drain stores before next tile
  }
}

extern "C" void kernel_launch(void* const* d_in, const int* in_sizes, int n_in,
                              void* d_out, int out_size, void* d_ws, size_t ws_size,
                              hipStream_t stream)
{
  const float* x  = (const float*)d_in[0];
  const float* ew = (const float*)d_in[1];
  const float* eb = (const float*)d_in[2];
  const float* rw = (const float*)d_in[3];
  const float* rb = (const float*)d_in[4];
  float* out = (float*)d_out;

  char* ws = (char*)d_ws;
  int*   eid    = (int*)(ws);                  // 8192 ints
  float* gate   = (float*)(ws + 32 * 1024);    // 8192 floats
  int*   counts = (int*)(ws + 64 * 1024);      // [0..7]
  int*   perm   = (int*)(ws + 128 * 1024);     // 8192 ints
  unsigned short* xbuf = (unsigned short*)(ws + 192 * 1024);   // 32 MB

  hipFuncSetAttribute(reinterpret_cast<const void*>(moe_gemm),
                      hipFuncAttributeMaxDynamicSharedMemorySize, DYN_LDS);

  hipMemsetAsync(out + (size_t)N_TOK * DIM, 0, sizeof(float), stream);      // loss = 0
  router_kernel<<<N_TOK / 4, 256, 0, stream>>>(x, rw, rb, eid, gate, xbuf);
  histo_perm<<<1, 1024, 0, stream>>>(eid, counts, perm);
  moe_gemm<<<NBLK, 512, DYN_LDS, stream>>>(xbuf, ew, eb, gate, perm, counts, out);
}

// Round 14
// 153.734 us; speedup vs baseline: 1.9155x; 1.0099x over previous
//
#include <hip/hip_runtime.h>
#include <hip/hip_bf16.h>

#define N_TOK 8192
#define DIM   2048
#define NEXP  8
#define BM    288          // sum ceil(c_e/288) == 32 for c_e in [865,1152]
#define BN    128          // 16 col-tiles -> ttot = 512 = exactly 2 tiles/CU
#define BK    32
#define NT    (DIM / BK)   // 64 K-steps
#define NBLK  512          // 2 blocks per CU (independent barriers -> phase drift)

#define A_BYTES  (BM * BK * 2)            // 18432 (A: bf16)
#define B_BYTES  (BN * BK * 4)            // 16384 (B: fp32, converted on LDS->reg read)
#define RING     (A_BYTES + B_BYTES)      // 34816
#define DYN_LDS  (2 * RING)               // 69632 (ring-2; 2 blocks/CU fit 160KB)

typedef __attribute__((ext_vector_type(8))) short  short8;
typedef __attribute__((ext_vector_type(4))) float  f32x4;
typedef __attribute__((ext_vector_type(4))) unsigned int u32x4;

static __device__ __forceinline__ unsigned int pack_bf2(float a, float b) {
  union { __hip_bfloat16 h; unsigned short u; } ca, cb;
  ca.h = __float2bfloat16(a);
  cb.h = __float2bfloat16(b);
  return ((unsigned int)cb.u << 16) | (unsigned int)ca.u;
}

static __device__ __forceinline__ void gload16(const void* g, void* l) {
  __builtin_amdgcn_global_load_lds(
      (const __attribute__((address_space(1))) unsigned int*)g,
      (__attribute__((address_space(3))) unsigned int*)l, 16, 0, 0);
}

static __device__ __forceinline__ double dot8d(const float4& x0, const float4& x1,
                                               const float4& w0, const float4& w1) {
  double a = 0.0;
  a = fma((double)x0.x, (double)w0.x, a);
  a = fma((double)x0.y, (double)w0.y, a);
  a = fma((double)x0.z, (double)w0.z, a);
  a = fma((double)x0.w, (double)w0.w, a);
  a = fma((double)x1.x, (double)w1.x, a);
  a = fma((double)x1.y, (double)w1.y, a);
  a = fma((double)x1.z, (double)w1.z, a);
  a = fma((double)x1.w, (double)w1.w, a);
  return a;
}

// ---------------- router (unchanged, round 8) ----------------
__global__ __launch_bounds__(256, 3) void router_kernel(
    const float* __restrict__ x, const float* __restrict__ rw,
    const float* __restrict__ rb, int* __restrict__ eid,
    float* __restrict__ gate, unsigned short* __restrict__ xb)
{
  const int t    = threadIdx.x;
  const int tok0 = blockIdx.x * 4;

  float4 w0[NEXP], w1[NEXP];
#pragma unroll
  for (int e = 0; e < NEXP; e++) {
    const float4* wr = reinterpret_cast<const float4*>(rw + (size_t)e * DIM);
    w0[e] = wr[2 * t];
    w1[e] = wr[2 * t + 1];
  }
  float4 xv0[4], xv1[4];
#pragma unroll
  for (int k = 0; k < 4; k++) {
    const float4* xr = reinterpret_cast<const float4*>(x + (size_t)(tok0 + k) * DIM);
    xv0[k] = xr[2 * t];
    xv1[k] = xr[2 * t + 1];
  }
#pragma unroll
  for (int k = 0; k < 4; k++) {
    u32x4 pk;
    pk[0] = pack_bf2(xv0[k].x, xv0[k].y); pk[1] = pack_bf2(xv0[k].z, xv0[k].w);
    pk[2] = pack_bf2(xv1[k].x, xv1[k].y); pk[3] = pack_bf2(xv1[k].z, xv1[k].w);
    *reinterpret_cast<u32x4*>(xb + (size_t)(tok0 + k) * DIM + t * 8) = pk;
  }

  __shared__ double red[4][4][NEXP];
  const int lane = t & 63, wv = t >> 6;
#pragma unroll
  for (int k = 0; k < 4; k++) {
    double s[NEXP];
#pragma unroll
    for (int e = 0; e < NEXP; e++) s[e] = dot8d(xv0[k], xv1[k], w0[e], w1[e]);
#pragma unroll
    for (int e = 0; e < NEXP; e++) {
      double v = s[e];
#pragma unroll
      for (int off = 32; off > 0; off >>= 1) v += __shfl_xor(v, off, 64);
      if (lane == 0) red[wv][k][e] = v;
    }
  }
  __syncthreads();
  if (t < 4) {
    double lg[NEXP];
    double lmax = -1e300; int best = 0;
#pragma unroll
    for (int e = 0; e < NEXP; e++) {
      lg[e] = red[0][t][e] + red[1][t][e] + red[2][t][e] + red[3][t][e] + (double)rb[e];
      if (lg[e] > lmax) { lmax = lg[e]; best = e; }   // strict > == first-occurrence argmax
    }
    float den = 0.f;
#pragma unroll
    for (int e = 0; e < NEXP; e++) den += expf((float)(lg[e] - lmax));
    eid[tok0 + t]  = best;
    gate[tok0 + t] = 1.0f / den;
  }
}

// ---------------- histo + permute (round 8; + writes loss=0) ----------------
__global__ __launch_bounds__(1024) void histo_perm(
    const int* __restrict__ eid, int* __restrict__ counts, int* __restrict__ perm,
    float* __restrict__ out)
{
  __shared__ int hist[NEXP], baseS[NEXP], fillS[NEXP];
  const int t = threadIdx.x;
  if (t < NEXP) { hist[t] = 0; fillS[t] = 0; }
  if (t == 64) out[(size_t)N_TOK * DIM] = 0.0f;    // loss output
  __syncthreads();
  int my[8];
#pragma unroll
  for (int i = 0; i < 8; i++) {
    my[i] = eid[t + i * 1024];
    atomicAdd(&hist[my[i]], 1);
  }
  __syncthreads();
  if (t == 0) {
    int b = 0;
#pragma unroll
    for (int e = 0; e < NEXP; e++) { counts[e] = hist[e]; baseS[e] = b; b += hist[e]; }
  }
  __syncthreads();
#pragma unroll
  for (int i = 0; i < 8; i++) {
    int pos = baseS[my[i]] + atomicAdd(&fillS[my[i]], 1);
    perm[pos] = t + i * 1024;
  }
}

// ------- grouped GEMM: 288x128 tile, 4 waves, ring-2, 2 blocks/CU (phase drift) ------
// A: bf16 from xb via global_load_lds.  B: fp32 W via global_load_lds (pre-swizzled
// source), converted bf16 on the LDS->reg path.  Per K-step: vmcnt(0) [loads issued a
// full step earlier -> ~free] -> s_barrier (publish slot t) -> stage t+1 -> read/MFMA t.
// Two independent blocks per CU drift out of phase -> LDS and matrix pipes overlap
// across blocks (m114 mechanism) without in-block register double-buffering (no spill).
__global__ __launch_bounds__(256, 2) void moe_gemm(
    const unsigned short* __restrict__ xb, const float* __restrict__ ew,
    const float* __restrict__ eb, const float* __restrict__ gate,
    const int* __restrict__ perm, const int* __restrict__ counts,
    float* __restrict__ out)
{
  extern __shared__ char smem[];     // 2 ring slots of {A 18432 B bf16 | B 16384 B fp32}
  __shared__ int   aRowS[BM];
  __shared__ float gateS[BM];

  const int tid  = threadIdx.x;
  const int lane = tid & 63, wid = tid >> 6;   // 4 waves

  int ttot = 0;
#pragma unroll
  for (int j = 0; j < NEXP; j++) ttot += (counts[j] + BM - 1) / BM;
  ttot *= 16;                                   // 16 col-tiles
  const int tq = ttot >> 3, tr = ttot & 7;

  // ---- A staging geometry: 18 chunks of 16 rows x 64B; waves 0-1: 5, waves 2-3: 4 ----
  const int nA5 = (wid < 2);
  int aC[5];
#pragma unroll
  for (int i = 0; i < 5; i++)
    aC[i] = (wid < 2) ? (wid * 5 + i) : (10 + (wid - 2) * 4 + ((i < 4) ? i : 0));
  int aDst[5];
#pragma unroll
  for (int i = 0; i < 5; i++) aDst[i] = aC[i] * 1024;
  const int lrowA = lane >> 2;                          // row within 16-row chunk
  const int cblkA = (lane & 3) ^ ((lane >> 3) & 3);     // pre-swizzled src (involution)

  // ---- B staging geometry: 16 chunks of 8 rows x 128B fp32; 4 per wave ----
  int bC[4];
#pragma unroll
  for (int i = 0; i < 4; i++) bC[i] = wid * 4 + i;
  int bDst[4];
#pragma unroll
  for (int i = 0; i < 4; i++) bDst[i] = A_BYTES + bC[i] * 1024;
  const int lrowB = lane >> 3;                          // row within 8-row chunk
  const int cblkB = (lane & 7) ^ (lrowB & 7);           // pre-swizzled src (involution)

  // ---- MFMA fragment addressing (2M x 2N waves; per-wave 144x64 output) ----
  const int l15 = lane & 15;
  const int wr = wid >> 1, wc = wid & 1;
  const int swA  = (((lane >> 4) ^ ((l15 >> 1) & 3)) * 16);   // A read-side swizzle
  const int aOff = (wr * 144 + l15) * 64 + swA;
  const int csB  = (lane >> 4) * 2;                           // fp32 16B-chunk pair base
  int bOffN[4];
#pragma unroll
  for (int n = 0; n < 4; n++) {
    int row = wc * 64 + n * 16 + l15;
    bOffN[n] = A_BYTES + row * 128 + ((csB ^ (row & 7)) << 4);   // pair: ^16
  }
  const int rsub = (lane >> 4) * 4;

  for (int ti = blockIdx.x; ti < ttot; ti += NBLK) {
    // ---- m204 bijective XCD remap: XCD k = ti&7 owns contiguous bx-major range ----
    const int k  = ti & 7, j = ti >> 3;
    const int tt = k * tq + (k < tr ? k : tr) + j;     // logical tile (bx-major)
    const int bx = tt >> 4, by = tt & 15;

    int e = 0, rowbase = 0, nrows = 0, found = 0;
    {
      int tsum = 0, bsum = 0;
#pragma unroll
      for (int jj = 0; jj < NEXP; jj++) {
        int cj = counts[jj];
        int te = (cj + BM - 1) / BM;
        if (!found && bx < tsum + te) {
          int loc = bx - tsum;
          e = jj;
          rowbase = bsum + loc * BM;
          int rem = cj - loc * BM;
          nrows = rem < BM ? rem : BM;
          found = 1;
        }
        tsum += te; bsum += cj;
      }
    }

    __syncthreads();   // prior tile fully done with aRowS/gateS and LDS slots
    for (int r = tid; r < BM; r += 256) {
      int idx = r < nrows ? r : (nrows - 1);
      int tok = perm[rowbase + idx];
      aRowS[r] = tok;
      gateS[r] = gate[tok];
    }
    __syncthreads();

    const float* wB32 = ew + (size_t)e * DIM * DIM;
    const unsigned short* aSrc[5];
    const float* bSrc[4];
#pragma unroll
    for (int i = 0; i < 5; i++)
      aSrc[i] = xb + (size_t)aRowS[aC[i] * 16 + lrowA] * DIM + cblkA * 8;
#pragma unroll
    for (int i = 0; i < 4; i++)
      bSrc[i] = wB32 + (size_t)(by * BN + bC[i] * 8 + lrowB) * DIM + cblkB * 4;

#define STAGE(SLOTP)                                                        \
    do {                                                                    \
      char* sb_ = (SLOTP);                                                  \
      gload16(aSrc[0], sb_ + aDst[0]);                                      \
      gload16(aSrc[1], sb_ + aDst[1]);                                      \
      gload16(aSrc[2], sb_ + aDst[2]);                                      \
      gload16(aSrc[3], sb_ + aDst[3]);                                      \
      if (nA5) gload16(aSrc[4], sb_ + aDst[4]);                             \
      gload16(bSrc[0], sb_ + bDst[0]);                                      \
      gload16(bSrc[1], sb_ + bDst[1]);                                      \
      gload16(bSrc[2], sb_ + bDst[2]);                                      \
      gload16(bSrc[3], sb_ + bDst[3]);                                      \
      aSrc[0] += BK; aSrc[1] += BK; aSrc[2] += BK; aSrc[3] += BK;           \
      aSrc[4] += BK;                                                        \
      bSrc[0] += BK; bSrc[1] += BK; bSrc[2] += BK; bSrc[3] += BK;           \
    } while (0)

    STAGE(smem);                      // stage K-step 0 into slot 0

    f32x4 acc[9][4] = {};

#pragma unroll 1
    for (int t = 0; t < NT; ++t) {
      // loads for slot t were issued one full step ago -> drain is ~free
      asm volatile("s_waitcnt vmcnt(0)" ::: "memory");
      __builtin_amdgcn_s_barrier();   // publish slot t; prior slot free

      if (t + 1 < NT) STAGE(smem + (size_t)((t + 1) & 1) * RING);

      const char* cur = smem + (size_t)(t & 1) * RING;

      // ---- B: fp32 ds_read + convert to bf16 frags ----
      f32x4 r0[4], r1[4];
#pragma unroll
      for (int n = 0; n < 4; n++) {
        r0[n] = *(const f32x4*)(cur + bOffN[n]);
        r1[n] = *(const f32x4*)(cur + (bOffN[n] ^ 16));
      }
      short8 bf[4];
#pragma unroll
      for (int n = 0; n < 4; n++) {
        u32x4 pk;
        pk[0] = pack_bf2(r0[n][0], r0[n][1]);
        pk[1] = pack_bf2(r0[n][2], r0[n][3]);
        pk[2] = pack_bf2(r1[n][0], r1[n][1]);
        pk[3] = pack_bf2(r1[n][2], r1[n][3]);
        union { u32x4 u; short8 s; } cv;
        cv.u = pk;
        bf[n] = cv.s;
      }
      // ---- A: bf16 ds_read frags ----
      short8 af[9];
#pragma unroll
      for (int m = 0; m < 9; m++) af[m] = *(const short8*)(cur + aOff + m * 1024);

      __builtin_amdgcn_s_setprio(1);
#pragma unroll
      for (int m = 0; m < 9; m++)
#pragma unroll
        for (int n = 0; n < 4; n++)
          acc[m][n] = __builtin_amdgcn_mfma_f32_16x16x32_bf16(af[m], bf[n], acc[m][n], 0, 0, 0);
      __builtin_amdgcn_s_setprio(0);
    }
#undef STAGE

    // ---- epilogue: +bias, *gate, scatter by token ----
    const int cb = by * BN + wc * 64;
    const float* ebE = eb + (size_t)e * DIM;
    float bias[4];
#pragma unroll
    for (int n = 0; n < 4; n++) bias[n] = ebE[cb + n * 16 + l15];
#pragma unroll
    for (int m = 0; m < 9; m++) {
      int r0w = wr * 144 + m * 16 + rsub;
#pragma unroll
      for (int rg = 0; rg < 4; rg++) {
        int r = r0w + rg;
        if (r < nrows) {
          float g = gateS[r];
          float* orow = out + (size_t)aRowS[r] * DIM + cb;
#pragma unroll
          for (int n = 0; n < 4; n++)
            orow[n * 16 + l15] = (acc[m][n][rg] + bias[n]) * g;
        }
      }
    }
    asm volatile("s_waitcnt vmcnt(0)" ::: "memory");   // drain stores before next tile
  }
}

extern "C" void kernel_launch(void* const* d_in, const int* in_sizes, int n_in,
                              void* d_out, int out_size, void* d_ws, size_t ws_size,
                              hipStream_t stream)
{
  const float* x  = (const float*)d_in[0];
  const float* ew = (const float*)d_in[1];
  const float* eb = (const float*)d_in[2];
  const float* rw = (const float*)d_in[3];
  const float* rb = (const float*)d_in[4];
  float* out = (float*)d_out;

  char* ws = (char*)d_ws;
  int*   eid    = (int*)(ws);                  // 8192 ints
  float* gate   = (float*)(ws + 32 * 1024);    // 8192 floats
  int*   counts = (int*)(ws + 64 * 1024);      // [0..7]
  int*   perm   = (int*)(ws + 128 * 1024);     // 8192 ints
  unsigned short* xbuf = (unsigned short*)(ws + 192 * 1024);   // 32 MB

  hipFuncSetAttribute(reinterpret_cast<const void*>(moe_gemm),
                      hipFuncAttributeMaxDynamicSharedMemorySize, DYN_LDS);

  router_kernel<<<N_TOK / 4, 256, 0, stream>>>(x, rw, rb, eid, gate, xbuf);
  histo_perm<<<1, 1024, 0, stream>>>(eid, counts, perm, out);
  moe_gemm<<<NBLK, 256, DYN_LDS, stream>>>(xbuf, ew, eb, gate, perm, counts, out);
}